// Round 3
// baseline (328.713 us; speedup 1.0000x reference)
//
#include <hip/hip_runtime.h>
#include <hip/hip_fp16.h>

// SpMM: out[r,:] = sum_{k: rows[k]==r} values[k] * weight[cols[k],:]  + bias
// Counting-sort nnz by row into (col,val) pairs; weight converted to fp16 in
// ws (halves gather bytes). Accum: 2 waves per row (column halves) x unroll-4
// nnz loop -> 32 waves/CU and 4 outstanding gathers/lane (latency-bound fix).

// ---- Fused: weight f32->f16 conversion (grid-stride, 8 floats/thread) + row histogram ----
__global__ void convert_count_kernel(const float* __restrict__ weight,
                                     __half* __restrict__ wf16, long long ngroups,
                                     const int* __restrict__ rows,
                                     int* __restrict__ counts, int nnz) {
    long long i = (long long)blockIdx.x * blockDim.x + threadIdx.x;
    if (i < nnz) atomicAdd(&counts[rows[(int)i]], 1);
    const float4* w4 = (const float4*)weight;
    float4* dst = (float4*)wf16;               // 16B = 8 halfs per group
    long long stride = (long long)gridDim.x * blockDim.x;
    for (long long g = i; g < ngroups; g += stride) {
        float4 a = w4[2 * g];
        float4 b = w4[2 * g + 1];
        union { __half2 h2[4]; float4 f4; } u;
        u.h2[0] = __floats2half2_rn(a.x, a.y);
        u.h2[1] = __floats2half2_rn(a.z, a.w);
        u.h2[2] = __floats2half2_rn(b.x, b.y);
        u.h2[3] = __floats2half2_rn(b.z, b.w);
        dst[g] = u.f4;
    }
}

// ---- Exclusive scan over counts (1 block); writes offsets AND cursor ----
__global__ void scan_kernel(const int* __restrict__ counts, int* __restrict__ offsets,
                            int* __restrict__ cursor, int n_rows) {
    __shared__ int partial[256];
    const int t = threadIdx.x;
    const int per = (n_rows + 255) / 256;
    const int base = t * per;
    int sum = 0;
    for (int j = 0; j < per; ++j) {
        int idx = base + j;
        if (idx < n_rows) sum += counts[idx];
    }
    partial[t] = sum;
    __syncthreads();
    for (int off = 1; off < 256; off <<= 1) {
        int v = 0;
        if (t >= off) v = partial[t - off];
        __syncthreads();
        if (t >= off) partial[t] += v;
        __syncthreads();
    }
    int run = (t == 0) ? 0 : partial[t - 1];
    for (int j = 0; j < per; ++j) {
        int idx = base + j;
        if (idx < n_rows) {
            offsets[idx] = run;
            cursor[idx] = run;
            run += counts[idx];
        }
    }
    if (t == 255) offsets[n_rows] = run;
}

// ---- Scatter nnz into row-sorted (col,val) pairs ----
__global__ void scatter_pairs_kernel(const int* __restrict__ rows, const int* __restrict__ cols,
                                     const float* __restrict__ values, int* __restrict__ cursor,
                                     int2* __restrict__ pairs, int nnz) {
    int i = blockIdx.x * blockDim.x + threadIdx.x;
    if (i < nnz) {
        int p = atomicAdd(&cursor[rows[i]], 1);
        pairs[p] = make_int2(cols[i], __float_as_int(values[i]));
    }
}

// ---- Accumulate: 2 waves per row (column halves), unroll-4 nnz loop ----
// Lane covers 4 fp16 cols (8B dwordx2 gather). Block = 256 thr = 4 waves = 2 rows.
__global__ __launch_bounds__(256) void accum_f16_kernel(
    const __half* __restrict__ wf16, const float* __restrict__ bias,
    const int* __restrict__ offsets, const int2* __restrict__ pairs,
    float* __restrict__ out, int out_f) {
    const int wave = threadIdx.x >> 6;
    const int lane = threadIdx.x & 63;
    const int row = blockIdx.x * 2 + (wave >> 1);
    const int half = wave & 1;                  // which 256-col half
    const int start = offsets[row];
    const int end   = offsets[row + 1];

    const int colbase = half * 256 + lane * 4;  // 4 halfs per lane
    const float2* wbase = (const float2*)wf16;  // one float2 = 4 halfs
    const int fidx = colbase >> 2;              // float2 index within a weight row
    const int frow = out_f >> 2;                // float2s per weight row (=128)

    float acc0 = 0.f, acc1 = 0.f, acc2 = 0.f, acc3 = 0.f;

    int p = start;
    for (; p + 4 <= end; p += 4) {
        int2 e0 = pairs[p];
        int2 e1 = pairs[p + 1];
        int2 e2 = pairs[p + 2];
        int2 e3 = pairs[p + 3];
        float2 w0 = wbase[(long long)e0.x * frow + fidx];
        float2 w1 = wbase[(long long)e1.x * frow + fidx];
        float2 w2 = wbase[(long long)e2.x * frow + fidx];
        float2 w3 = wbase[(long long)e3.x * frow + fidx];
        float v0 = __int_as_float(e0.y);
        float v1 = __int_as_float(e1.y);
        float v2 = __int_as_float(e2.y);
        float v3 = __int_as_float(e3.y);
        {
            const __half2* h = (const __half2*)&w0;
            float2 a = __half22float2(h[0]), b = __half22float2(h[1]);
            acc0 += v0 * a.x; acc1 += v0 * a.y; acc2 += v0 * b.x; acc3 += v0 * b.y;
        }
        {
            const __half2* h = (const __half2*)&w1;
            float2 a = __half22float2(h[0]), b = __half22float2(h[1]);
            acc0 += v1 * a.x; acc1 += v1 * a.y; acc2 += v1 * b.x; acc3 += v1 * b.y;
        }
        {
            const __half2* h = (const __half2*)&w2;
            float2 a = __half22float2(h[0]), b = __half22float2(h[1]);
            acc0 += v2 * a.x; acc1 += v2 * a.y; acc2 += v2 * b.x; acc3 += v2 * b.y;
        }
        {
            const __half2* h = (const __half2*)&w3;
            float2 a = __half22float2(h[0]), b = __half22float2(h[1]);
            acc0 += v3 * a.x; acc1 += v3 * a.y; acc2 += v3 * b.x; acc3 += v3 * b.y;
        }
    }
    for (; p < end; ++p) {
        int2 e0 = pairs[p];
        float v0 = __int_as_float(e0.y);
        float2 w0 = wbase[(long long)e0.x * frow + fidx];
        const __half2* h = (const __half2*)&w0;
        float2 a = __half22float2(h[0]), b = __half22float2(h[1]);
        acc0 += v0 * a.x; acc1 += v0 * a.y; acc2 += v0 * b.x; acc3 += v0 * b.y;
    }

    float4 bv = *(const float4*)(bias + colbase);
    float4 o = make_float4(acc0 + bv.x, acc1 + bv.y, acc2 + bv.z, acc3 + bv.w);
    *(float4*)(out + (long long)row * out_f + colbase) = o;
}

// ================= Fallback path (ws too small): f32 atomic-free scheme =================
__global__ void count_rows_kernel(const int* __restrict__ rows, int* __restrict__ counts, int nnz) {
    int i = blockIdx.x * blockDim.x + threadIdx.x;
    if (i < nnz) atomicAdd(&counts[rows[i]], 1);
}
__global__ void scatter_kernel(const int* __restrict__ rows, int* __restrict__ cursor,
                               int* __restrict__ perm, int nnz) {
    int i = blockIdx.x * blockDim.x + threadIdx.x;
    if (i < nnz) {
        int p = atomicAdd(&cursor[rows[i]], 1);
        perm[p] = i;
    }
}
__global__ void accum_kernel(const float* __restrict__ values, const float* __restrict__ weight,
                             const float* __restrict__ bias, const int* __restrict__ cols,
                             const int* __restrict__ offsets, const int* __restrict__ perm,
                             float* __restrict__ out, int out_f) {
    const int r = blockIdx.x;
    const int start = offsets[r];
    const int end = offsets[r + 1];
    const int step = blockDim.x * 4;
    for (int base = threadIdx.x * 4; base < out_f; base += step) {
        float4 acc = make_float4(0.f, 0.f, 0.f, 0.f);
        for (int p = start; p < end; ++p) {
            int k = perm[p];
            float v = values[k];
            long long c = cols[k];
            float4 w = *(const float4*)(weight + c * (long long)out_f + base);
            acc.x += v * w.x; acc.y += v * w.y; acc.z += v * w.z; acc.w += v * w.w;
        }
        float4 b = *(const float4*)(bias + base);
        acc.x += b.x; acc.y += b.y; acc.z += b.z; acc.w += b.w;
        *(float4*)(out + (long long)r * out_f + base) = acc;
    }
}

static size_t align_up(size_t x, size_t a) { return (x + a - 1) & ~(a - 1); }

extern "C" void kernel_launch(void* const* d_in, const int* in_sizes, int n_in,
                              void* d_out, int out_size, void* d_ws, size_t ws_size,
                              hipStream_t stream) {
    const float* values = (const float*)d_in[0];
    const float* weight = (const float*)d_in[1];
    const float* bias   = (const float*)d_in[2];
    const int*   rows   = (const int*)d_in[3];
    const int*   cols   = (const int*)d_in[4];

    const int nnz = in_sizes[0];
    const long long wtotal = in_sizes[1];
    const int out_f = in_sizes[2];
    const int n_rows = out_size / out_f;
    float* out = (float*)d_out;

    // ws layout: wf16[wtotal] | counts[n_rows] | offsets[n_rows+1] | cursor[n_rows] | pairs[nnz]
    size_t off_wf16 = 0;
    size_t off_counts = align_up(off_wf16 + (size_t)wtotal * sizeof(__half), 256);
    size_t off_offsets = off_counts + (size_t)n_rows * sizeof(int);
    size_t off_cursor = off_offsets + (size_t)(n_rows + 1) * sizeof(int);
    size_t off_pairs = align_up(off_cursor + (size_t)n_rows * sizeof(int), 256);
    size_t need = off_pairs + (size_t)nnz * sizeof(int2);

    if (ws_size >= need && out_f == 512 && (n_rows % 2) == 0) {
        char* ws = (char*)d_ws;
        __half* wf16 = (__half*)(ws + off_wf16);
        int* counts = (int*)(ws + off_counts);
        int* offsets = (int*)(ws + off_offsets);
        int* cursor = (int*)(ws + off_cursor);
        int2* pairs = (int2*)(ws + off_pairs);

        hipMemsetAsync(counts, 0, (size_t)n_rows * sizeof(int), stream);

        long long ngroups = wtotal / 8;
        int cc_blocks = (int)((ngroups + 255) / 256);
        convert_count_kernel<<<cc_blocks, 256, 0, stream>>>(weight, wf16, ngroups,
                                                            rows, counts, nnz);
        scan_kernel<<<1, 256, 0, stream>>>(counts, offsets, cursor, n_rows);
        int sc_blocks = (nnz + 255) / 256;
        scatter_pairs_kernel<<<sc_blocks, 256, 0, stream>>>(rows, cols, values, cursor,
                                                            pairs, nnz);
        // 2 rows per block (4 waves: 2 rows x 2 column-halves)
        accum_f16_kernel<<<n_rows / 2, 256, 0, stream>>>(wf16, bias, offsets, pairs,
                                                         out, out_f);
    } else {
        // f32 fallback: counts | offsets | cursor | perm
        int* counts = (int*)d_ws;
        int* offsets = counts + n_rows;
        int* cursor = offsets + n_rows + 1;
        int* perm = cursor + n_rows;
        hipMemsetAsync(counts, 0, (size_t)n_rows * sizeof(int), stream);
        int blocks = (nnz + 255) / 256;
        count_rows_kernel<<<blocks, 256, 0, stream>>>(rows, counts, nnz);
        scan_kernel<<<1, 256, 0, stream>>>(counts, offsets, cursor, n_rows);
        scatter_kernel<<<blocks, 256, 0, stream>>>(rows, cursor, perm, nnz);
        accum_kernel<<<n_rows, 128, 0, stream>>>(values, weight, bias, cols,
                                                 offsets, perm, out, out_f);
    }
}